// Round 1
// baseline (185.177 us; speedup 1.0000x reference)
//
#include <hip/hip_runtime.h>
#include <hip/hip_bf16.h>

// NT-Xent loss, N=4096, D=256, T=0.5.
// z = concat(z_i, z_j) (8192 x 256). loss = mean_r [ LSE_{c!=r}(2 z_r.z_c) - 2 z_r.z_label(r) ]
// Flash-style streaming logsumexp over the implicit 8192x8192 sim matrix using bf16 MFMA.

typedef __bf16 bf16x8 __attribute__((ext_vector_type(8)));
typedef __bf16 bf16x4 __attribute__((ext_vector_type(4)));
typedef float  f32x16 __attribute__((ext_vector_type(16)));

#define NPAIR 4096
#define NROW  8192
#define DIM   256
#define NSPLIT 8
#define NEGF  (-1.0e30f)
// sim = dot / T = 2*dot ; work in base-2: x = sim * log2(e) = dot * 2*log2(e)
#define SCALE2 2.8853900817779268f
#define LN2F   0.6931471805599453f

// ---------------- kernel 1: f32 -> bf16 convert + positive-pair dots ----------------
// one wave per pair-row r: writes Z[r] (bf16 of z_i[r]) and Z[r+NPAIR] (bf16 of z_j[r]),
// pos[r] = 2 * dot(z_i[r], z_j[r]) in fp32.
__global__ __launch_bounds__(256) void k_convert(const float* __restrict__ zi,
                                                 const float* __restrict__ zj,
                                                 __bf16* __restrict__ Z,
                                                 float* __restrict__ pos) {
    const int w = threadIdx.x >> 6, lane = threadIdx.x & 63;
    const int r = blockIdx.x * 4 + w;
    const float4 vi = *(const float4*)(zi + r * DIM + lane * 4);
    const float4 vj = *(const float4*)(zj + r * DIM + lane * 4);
    bf16x4 bi, bj;
    bi[0] = (__bf16)vi.x; bi[1] = (__bf16)vi.y; bi[2] = (__bf16)vi.z; bi[3] = (__bf16)vi.w;
    bj[0] = (__bf16)vj.x; bj[1] = (__bf16)vj.y; bj[2] = (__bf16)vj.z; bj[3] = (__bf16)vj.w;
    *(bf16x4*)(Z + r * DIM + lane * 4) = bi;
    *(bf16x4*)(Z + (r + NPAIR) * DIM + lane * 4) = bj;
    float d = vi.x * vj.x + vi.y * vj.y + vi.z * vj.z + vi.w * vj.w;
    #pragma unroll
    for (int m = 32; m >= 1; m >>= 1) d += __shfl_xor(d, m);
    if (lane == 0) pos[r] = 2.0f * d;
}

// ---------------- kernel 2: streaming logsumexp over sim rows ----------------
// grid = 32 row-blocks x 8 column-splits. block = 4 waves; each wave: 64 rows
// (two 32-row MFMA accumulator sets). A fragments (64 rows x 256) live in VGPRs
// for the whole block; B fragments read directly from global (Z is L2-resident).
__global__ __launch_bounds__(256, 1) void k_lse(const __bf16* __restrict__ Z,
                                                float* __restrict__ Mpart,
                                                float* __restrict__ Lpart) {
    const int split = blockIdx.x & (NSPLIT - 1);
    const int rb    = blockIdx.x >> 3;
    const int w     = threadIdx.x >> 6;
    const int lane  = threadIdx.x & 63;
    const int lm    = lane & 31;       // MFMA m/n lane coordinate
    const int half  = lane >> 5;       // k-half for A/B fragments
    const int wavebase = rb * 256 + w * 64;
    const int colbase0 = split * (NROW / NSPLIT);   // 1024-column range

    // A fragments: A[m=lane&31][k=(lane>>5)*8+j]; any error in the assumed
    // lane->k map cancels because B uses the identical formula.
    bf16x8 A[2][16];
    #pragma unroll
    for (int s = 0; s < 2; s++)
        #pragma unroll
        for (int t = 0; t < 16; t++)
            A[s][t] = *(const bf16x8*)(Z + (wavebase + s * 32 + lm) * DIM + t * 16 + half * 8);

    // per-lane online LSE state: one (m,l) per accumulator register (fixed row).
    float m[2][16], l[2][16];
    #pragma unroll
    for (int s = 0; s < 2; s++)
        #pragma unroll
        for (int rg = 0; rg < 16; rg++) { m[s][rg] = NEGF; l[s][rg] = 0.0f; }

    for (int ct = 0; ct < 32; ct++) {
        const int colbase = colbase0 + ct * 32;
        const __bf16* bp = Z + (colbase + lm) * DIM + half * 8;
        f32x16 acc0 = {0.f,0.f,0.f,0.f,0.f,0.f,0.f,0.f,0.f,0.f,0.f,0.f,0.f,0.f,0.f,0.f};
        f32x16 acc1 = acc0;
        #pragma unroll
        for (int t = 0; t < 16; t++) {
            bf16x8 b = *(const bf16x8*)(bp + t * 16);
            acc0 = __builtin_amdgcn_mfma_f32_32x32x16_bf16(A[0][t], b, acc0, 0, 0, 0);
            acc1 = __builtin_amdgcn_mfma_f32_32x32x16_bf16(A[1][t], b, acc1, 0, 0, 0);
        }
        const int col = colbase + lm;
        // C/D layout (HW-verified): col = lane&31, row = (reg&3) + 8*(reg>>2) + 4*(lane>>5)
        #pragma unroll
        for (int s = 0; s < 2; s++) {
            const int rbase = wavebase + s * 32 + 4 * half;
            #pragma unroll
            for (int rg = 0; rg < 16; rg++) {
                const int r = rbase + (rg & 3) + 8 * (rg >> 2);
                float x = (s ? acc1[rg] : acc0[rg]) * SCALE2;
                x = (r == col) ? NEGF : x;   // mask diagonal (self-similarity)
                const float mo = m[s][rg];
                const float mn = fmaxf(mo, x);
                // spurious exp2(0)=1 when mo==x==NEGF is annihilated by the
                // l*exp2(NEGF - real) = 0 rescale on the next real element.
                l[s][rg] = l[s][rg] * __builtin_exp2f(mo - mn) + __builtin_exp2f(x - mn);
                m[s][rg] = mn;
            }
        }
    }

    // butterfly-merge the 32 per-lane states of each row (within each 32-lane half)
    #pragma unroll
    for (int s = 0; s < 2; s++)
        #pragma unroll
        for (int rg = 0; rg < 16; rg++) {
            float mm = m[s][rg], ll = l[s][rg];
            #pragma unroll
            for (int d = 1; d < 32; d <<= 1) {
                const float mo = __shfl_xor(mm, d);
                const float lo = __shfl_xor(ll, d);
                const float mn = fmaxf(mm, mo);
                ll = ll * __builtin_exp2f(mm - mn) + lo * __builtin_exp2f(mo - mn);
                mm = mn;
            }
            if (lm == 0) {
                const int r = wavebase + s * 32 + 4 * half + (rg & 3) + 8 * (rg >> 2);
                Mpart[split * NROW + r] = mm;
                Lpart[split * NROW + r] = ll;
            }
        }
}

// ---------------- kernel 3: merge splits, per-row loss, global mean ----------------
__global__ __launch_bounds__(1024) void k_final(const float* __restrict__ Mpart,
                                                const float* __restrict__ Lpart,
                                                const float* __restrict__ pos,
                                                float* __restrict__ out) {
    __shared__ float red[1024];
    const int t = threadIdx.x;
    float local = 0.0f;
    #pragma unroll
    for (int q = 0; q < 8; q++) {
        const int r = t + q * 1024;
        float mm = NEGF, ss = 0.0f;
        #pragma unroll
        for (int sp = 0; sp < NSPLIT; sp++) {
            const float mi = Mpart[sp * NROW + r];
            const float li = Lpart[sp * NROW + r];
            const float mn = fmaxf(mm, mi);
            ss = ss * __builtin_exp2f(mm - mn) + li * __builtin_exp2f(mi - mn);
            mm = mn;
        }
        const float lse = (mm + __builtin_log2f(ss)) * LN2F;   // natural-log LSE
        local += lse - pos[r & (NPAIR - 1)];
    }
    red[t] = local;
    __syncthreads();
    for (int ofs = 512; ofs > 0; ofs >>= 1) {
        if (t < ofs) red[t] += red[t + ofs];
        __syncthreads();
    }
    if (t == 0) out[0] = red[0] / (float)NROW;
}

extern "C" void kernel_launch(void* const* d_in, const int* in_sizes, int n_in,
                              void* d_out, int out_size, void* d_ws, size_t ws_size,
                              hipStream_t stream) {
    const float* zi = (const float*)d_in[0];
    const float* zj = (const float*)d_in[1];
    __bf16* Z    = (__bf16*)d_ws;                       // 8192*256 bf16 = 4 MB
    float* pos   = (float*)((char*)d_ws + (size_t)NROW * DIM * 2);
    float* Mpart = pos + NPAIR;
    float* Lpart = Mpart + NSPLIT * NROW;

    k_convert<<<NPAIR / 4, 256, 0, stream>>>(zi, zj, Z, pos);
    k_lse<<<(NROW / 256) * NSPLIT, 256, 0, stream>>>(Z, Mpart, Lpart);
    k_final<<<1, 1024, 0, stream>>>(Mpart, Lpart, pos, (float*)d_out);
}

// Round 2
// 134.387 us; speedup vs baseline: 1.3779x; 1.3779x over previous
//
#include <hip/hip_runtime.h>
#include <hip/hip_bf16.h>

// NT-Xent loss, N=4096, D=256, T=0.5.
// z = concat(z_i, z_j) (8192 x 256). loss = mean_r [ LSE_{c!=r}(2 z_r.z_c) - 2 z_r.z_label(r) ]
// Flash-style streaming logsumexp. Key layout trick: stream COLUMNS through the
// MFMA A-operand, keep the wave's 64 rows fixed in the B-operand -> each lane's
// 16 acc regs are 16 columns of ONE row, so online-LSE state is 2x(m,l) per lane.

typedef __bf16 bf16x8 __attribute__((ext_vector_type(8)));
typedef __bf16 bf16x4 __attribute__((ext_vector_type(4)));
typedef float  f32x16 __attribute__((ext_vector_type(16)));

#define NPAIR 4096
#define NROW  8192
#define DIM   256
#define NSPLIT 16
#define SPLITCOLS (NROW / NSPLIT)   // 512
#define NEGF  (-1.0e30f)
// sim/T in base-2: x = dot * 2*log2(e). Z is pre-scaled by sqrt(2*log2 e) so
// the MFMA accumulator IS x directly.
#define SQSCALE 1.6986437f
#define LN2F    0.6931471805599453f

// ---------------- kernel 1: f32 -> bf16 convert (pre-scaled) + positive-pair dots ----
__global__ __launch_bounds__(256) void k_convert(const float* __restrict__ zi,
                                                 const float* __restrict__ zj,
                                                 __bf16* __restrict__ Z,
                                                 float* __restrict__ pos) {
    const int w = threadIdx.x >> 6, lane = threadIdx.x & 63;
    const int r = blockIdx.x * 4 + w;
    const float4 vi = *(const float4*)(zi + r * DIM + lane * 4);
    const float4 vj = *(const float4*)(zj + r * DIM + lane * 4);
    bf16x4 bi, bj;
    bi[0] = (__bf16)(vi.x * SQSCALE); bi[1] = (__bf16)(vi.y * SQSCALE);
    bi[2] = (__bf16)(vi.z * SQSCALE); bi[3] = (__bf16)(vi.w * SQSCALE);
    bj[0] = (__bf16)(vj.x * SQSCALE); bj[1] = (__bf16)(vj.y * SQSCALE);
    bj[2] = (__bf16)(vj.z * SQSCALE); bj[3] = (__bf16)(vj.w * SQSCALE);
    *(bf16x4*)(Z + r * DIM + lane * 4) = bi;
    *(bf16x4*)(Z + (r + NPAIR) * DIM + lane * 4) = bj;
    float d = vi.x * vj.x + vi.y * vj.y + vi.z * vj.z + vi.w * vj.w;
    #pragma unroll
    for (int m = 32; m >= 1; m >>= 1) d += __shfl_xor(d, m);
    if (lane == 0) pos[r] = 2.0f * d;   // natural units (un-scaled dot * 2)
}

// ---------------- kernel 2: streaming logsumexp ----------------
// grid = 32 row-blocks x 16 column-splits = 512 blocks (2 blocks/CU).
// block = 4 waves; wave owns 64 rows (B-operand, fixed in 128 VGPRs) and
// streams 16 tiles of 32 columns (A-operand, straight from L2-resident Z).
__global__ __launch_bounds__(256, 2) void k_lse(const __bf16* __restrict__ Z,
                                                float* __restrict__ Mpart,
                                                float* __restrict__ Lpart) {
    const int split = blockIdx.x & (NSPLIT - 1);
    const int rb    = blockIdx.x >> 4;
    const int w     = threadIdx.x >> 6;
    const int lane  = threadIdx.x & 63;
    const int lm    = lane & 31;
    const int half  = lane >> 5;
    const int wavebase = rb * 256 + w * 64;
    const int colbase0 = split * SPLITCOLS;

    // fixed row fragments (B-operand): row = wavebase + s*32 + lm, k-chunk t
    bf16x8 Bf[2][16];
    #pragma unroll
    for (int s = 0; s < 2; s++)
        #pragma unroll
        for (int t = 0; t < 16; t++)
            Bf[s][t] = *(const bf16x8*)(Z + (wavebase + s * 32 + lm) * DIM + t * 16 + half * 8);

    // per-lane online LSE: row(s) = wavebase + s*32 + lm (this lane's half of its cols)
    float m[2] = {NEGF, NEGF}, l[2] = {0.0f, 0.0f};

    for (int ct = 0; ct < SPLITCOLS / 32; ct++) {
        const int colbase = colbase0 + ct * 32;
        const __bf16* ap = Z + (colbase + lm) * DIM + half * 8;
        f32x16 acc0 = {0.f,0.f,0.f,0.f,0.f,0.f,0.f,0.f,0.f,0.f,0.f,0.f,0.f,0.f,0.f,0.f};
        f32x16 acc1 = acc0;
        #pragma unroll
        for (int t = 0; t < 16; t++) {
            bf16x8 a = *(const bf16x8*)(ap + t * 16);
            acc0 = __builtin_amdgcn_mfma_f32_32x32x16_bf16(a, Bf[0][t], acc0, 0, 0, 0);
            acc1 = __builtin_amdgcn_mfma_f32_32x32x16_bf16(a, Bf[1][t], acc1, 0, 0, 0);
        }
        // D[c][r]: out-col (lane&31) = r_local, out-row ((rg&3)+8*(rg>>2)+4*half) = c_local
        const bool dtile = (unsigned)(colbase - wavebase) < 64u;  // tile contains diagonal?
        #pragma unroll
        for (int s = 0; s < 2; s++) {
            float x[16];
            #pragma unroll
            for (int rg = 0; rg < 16; rg++) x[rg] = (s ? acc1[rg] : acc0[rg]);
            if (dtile) {
                const int r = wavebase + s * 32 + lm;
                #pragma unroll
                for (int rg = 0; rg < 16; rg++) {
                    const int c = colbase + (rg & 3) + 8 * (rg >> 2) + 4 * half;
                    x[rg] = (c == r) ? NEGF : x[rg];
                }
            }
            // tile max (tree)
            float t8[8], t4[4], t2[2];
            #pragma unroll
            for (int i = 0; i < 8; i++) t8[i] = fmaxf(x[i], x[i + 8]);
            #pragma unroll
            for (int i = 0; i < 4; i++) t4[i] = fmaxf(t8[i], t8[i + 4]);
            t2[0] = fmaxf(t4[0], t4[2]); t2[1] = fmaxf(t4[1], t4[3]);
            const float tmax = fmaxf(t2[0], t2[1]);
            const float mn = fmaxf(m[s], tmax);
            float acc_l = l[s] * __builtin_exp2f(m[s] - mn);   // 0 on first tile
            float e[16];
            #pragma unroll
            for (int rg = 0; rg < 16; rg++) e[rg] = __builtin_exp2f(x[rg] - mn);
            float s8[8], s4[4], s2[2];
            #pragma unroll
            for (int i = 0; i < 8; i++) s8[i] = e[i] + e[i + 8];
            #pragma unroll
            for (int i = 0; i < 4; i++) s4[i] = s8[i] + s8[i + 4];
            s2[0] = s4[0] + s4[2]; s2[1] = s4[1] + s4[3];
            l[s] = acc_l + (s2[0] + s2[1]);
            m[s] = mn;
        }
    }

    // merge the two k-halves (lane <-> lane^32 hold same row, disjoint col sets)
    float mw[2], lw[2];
    #pragma unroll
    for (int s = 0; s < 2; s++) {
        const float mo = __shfl_xor(m[s], 32);
        const float lo = __shfl_xor(l[s], 32);
        const float mn = fmaxf(m[s], mo);
        lw[s] = l[s] * __builtin_exp2f(m[s] - mn) + lo * __builtin_exp2f(mo - mn);
        mw[s] = mn;
    }
    const int r_out = wavebase + half * 32 + lm;     // 64 distinct rows per wave
    Mpart[split * NROW + r_out] = mw[half];
    Lpart[split * NROW + r_out] = lw[half];
}

// ---------------- kernel 3a: zero the output accumulator ----------------
__global__ void k_zero(float* out) { out[0] = 0.0f; }

// ---------------- kernel 3b: merge splits, per-row loss, atomic mean ----------------
__global__ __launch_bounds__(256) void k_final(const float* __restrict__ Mpart,
                                               const float* __restrict__ Lpart,
                                               const float* __restrict__ pos,
                                               float* __restrict__ out) {
    __shared__ float red[256];
    const int t = threadIdx.x;
    const int r = blockIdx.x * 256 + t;
    float mm = NEGF, ss = 0.0f;
    #pragma unroll
    for (int sp = 0; sp < NSPLIT; sp++) {
        const float mi = Mpart[sp * NROW + r];
        const float li = Lpart[sp * NROW + r];
        const float mn = fmaxf(mm, mi);
        ss = ss * __builtin_exp2f(mm - mn) + li * __builtin_exp2f(mi - mn);
        mm = mn;
    }
    const float lse = (mm + __builtin_log2f(ss)) * LN2F;
    red[t] = lse - pos[r & (NPAIR - 1)];
    __syncthreads();
    for (int ofs = 128; ofs > 0; ofs >>= 1) {
        if (t < ofs) red[t] += red[t + ofs];
        __syncthreads();
    }
    if (t == 0) atomicAdd(out, red[0] / (float)NROW);
}

extern "C" void kernel_launch(void* const* d_in, const int* in_sizes, int n_in,
                              void* d_out, int out_size, void* d_ws, size_t ws_size,
                              hipStream_t stream) {
    const float* zi = (const float*)d_in[0];
    const float* zj = (const float*)d_in[1];
    __bf16* Z    = (__bf16*)d_ws;                       // 8192*256 bf16 = 4 MB
    float* pos   = (float*)((char*)d_ws + (size_t)NROW * DIM * 2);
    float* Mpart = pos + NPAIR;
    float* Lpart = Mpart + NSPLIT * NROW;

    k_convert<<<NPAIR / 4, 256, 0, stream>>>(zi, zj, Z, pos);
    k_lse<<<(NROW / 256) * NSPLIT, 256, 0, stream>>>(Z, Mpart, Lpart);
    k_zero<<<1, 1, 0, stream>>>((float*)d_out);
    k_final<<<NROW / 256, 256, 0, stream>>>(Mpart, Lpart, pos, (float*)d_out);
}

// Round 3
// 123.847 us; speedup vs baseline: 1.4952x; 1.0851x over previous
//
#include <hip/hip_runtime.h>
#include <hip/hip_bf16.h>

// NT-Xent loss, N=4096, D=256, T=0.5.
// loss = mean_r [ LSE_{c!=r}(2 z_r.z_c) - 2 z_r.z_label(r) ], z = concat(z_i,z_j) (8192x256)
// Flash-style streaming LSE with bf16 MFMA. This revision:
//  - Z stored in FRAGMENT-READY layout Z_F[(row>>5)][t][half][row&31] (16-B units)
//    so both A (streamed cols) and B (resident rows) loads are lane-contiguous.
//  - 128 rows per wave (4 acc sets), 1 wave/SIMD, B-frags resident in 256 VGPRs.
//  - A-tiles register-double-buffered in half-tile batches; no LDS, no barriers.

typedef __bf16 bf16x8 __attribute__((ext_vector_type(8)));
typedef __bf16 bf16x4 __attribute__((ext_vector_type(4)));
typedef float  f32x16 __attribute__((ext_vector_type(16)));

#define NPAIR 4096
#define NROW  8192
#define DIM   256
#define NSPLIT 16
#define SPLITCOLS 512
#define NTILES (SPLITCOLS / 32)   // 16 tiles of 32 cols per split
#define RBLK  16384               // bytes per 32-row fragment block (32*256*2)
#define NEGF  (-1.0e30f)
// x = dot/T * log2(e) = dot * 2*log2(e); Z pre-scaled by sqrt(2*log2 e)
#define SQSCALE 1.6986437f
#define LN2F    0.6931471805599453f

// ---------- kernel 1: f32 -> bf16 (pre-scaled) into Z_F + positive dots + out zero ----
__global__ __launch_bounds__(256) void k_convert(const float* __restrict__ zi,
                                                 const float* __restrict__ zj,
                                                 __bf16* __restrict__ Zf,
                                                 float* __restrict__ pos,
                                                 float* __restrict__ out) {
    const int w = threadIdx.x >> 6, lane = threadIdx.x & 63;
    const int r = blockIdx.x * 4 + w;
    if (blockIdx.x == 0 && threadIdx.x == 0) out[0] = 0.0f;
    const float4 vi = *(const float4*)(zi + r * DIM + lane * 4);
    const float4 vj = *(const float4*)(zj + r * DIM + lane * 4);
    bf16x4 bi, bj;
    bi[0] = (__bf16)(vi.x * SQSCALE); bi[1] = (__bf16)(vi.y * SQSCALE);
    bi[2] = (__bf16)(vi.z * SQSCALE); bi[3] = (__bf16)(vi.w * SQSCALE);
    bj[0] = (__bf16)(vj.x * SQSCALE); bj[1] = (__bf16)(vj.y * SQSCALE);
    bj[2] = (__bf16)(vj.z * SQSCALE); bj[3] = (__bf16)(vj.w * SQSCALE);
    // lane holds k = lane*4..lane*4+3 -> chunk t = lane>>2, half = (lane>>1)&1, inner = (lane&1)*8 bytes
    const int t = lane >> 2, h = (lane >> 1) & 1, inner = (lane & 1) * 8;
    char* Zb = (char*)Zf;
    *(bf16x4*)(Zb + (size_t)(r >> 5) * RBLK + t * 1024 + h * 512 + (r & 31) * 16 + inner) = bi;
    const int r2 = r + NPAIR;
    *(bf16x4*)(Zb + (size_t)(r2 >> 5) * RBLK + t * 1024 + h * 512 + (r2 & 31) * 16 + inner) = bj;
    float d = vi.x * vj.x + vi.y * vj.y + vi.z * vj.z + vi.w * vj.w;
    #pragma unroll
    for (int m = 32; m >= 1; m >>= 1) d += __shfl_xor(d, m);
    if (lane == 0) pos[r] = 2.0f * d;   // natural units
}

// ---------- kernel 2: streaming logsumexp ----------
// grid = 16 rowblocks x 16 splits = 256 blocks (1/CU). block = 4 waves; each wave
// owns 128 rows (4 MFMA sets, B-operand resident in 256 VGPRs) and streams 16
// tiles of 32 columns through the A-operand from L1/L2 (coalesced Z_F loads).
__global__ __launch_bounds__(256, 1) void k_lse(const __bf16* __restrict__ Zf,
                                                float* __restrict__ Mpart,
                                                float* __restrict__ Lpart) {
    const int sp = blockIdx.x & (NSPLIT - 1);
    const int rb = blockIdx.x >> 4;
    const int w    = threadIdx.x >> 6;
    const int lane = threadIdx.x & 63;
    const int lm   = lane & 31;
    const int half = lane >> 5;
    const int rbase = rb * 512 + w * 128;
    const char* Zb = (const char*)Zf;
    const int laneoff = half * 512 + lm * 16;

    // resident row fragments: set s covers rows rbase + s*32 + (0..31)
    bf16x8 Bf[4][16];
    #pragma unroll
    for (int s = 0; s < 4; s++)
        #pragma unroll
        for (int t = 0; t < 16; t++)
            Bf[s][t] = *(const bf16x8*)(Zb + (size_t)(rb * 16 + w * 4 + s) * RBLK + t * 1024 + laneoff);

    float m[4], l[4];
    #pragma unroll
    for (int s = 0; s < 4; s++) { m[s] = NEGF; l[s] = 0.0f; }

    const char* Ab = Zb + (size_t)(sp * NTILES) * RBLK + laneoff;

    // prologue: chunks 0..7 of tile 0
    bf16x8 Ah[8], Bh[8];
    #pragma unroll
    for (int t = 0; t < 8; t++) Ah[t] = *(const bf16x8*)(Ab + t * 1024);

    for (int ct = 0; ct < NTILES; ct++) {
        const char* At = Ab + (size_t)ct * RBLK;
        f32x16 acc[4];
        #pragma unroll
        for (int s = 0; s < 4; s++) acc[s] = (f32x16)(0.0f);

        // issue loads for chunks 8..15 of this tile, covered by first 32 MFMAs
        #pragma unroll
        for (int t = 0; t < 8; t++) Bh[t] = *(const bf16x8*)(At + (t + 8) * 1024);
        #pragma unroll
        for (int t = 0; t < 8; t++) {
            #pragma unroll
            for (int s = 0; s < 4; s++)
                acc[s] = __builtin_amdgcn_mfma_f32_32x32x16_bf16(Ah[t], Bf[s][t], acc[s], 0, 0, 0);
        }
        // prefetch chunks 0..7 of next tile, covered by second 32 MFMAs
        if (ct < NTILES - 1) {
            #pragma unroll
            for (int t = 0; t < 8; t++) Ah[t] = *(const bf16x8*)(At + RBLK + t * 1024);
        }
        #pragma unroll
        for (int t = 0; t < 8; t++) {
            #pragma unroll
            for (int s = 0; s < 4; s++)
                acc[s] = __builtin_amdgcn_mfma_f32_32x32x16_bf16(Bh[t], Bf[s][t + 8], acc[s], 0, 0, 0);
        }

        // epilogue: per lane, set s -> row rbase+s*32+lm, 16 cols (by reg & half)
        const int cb = sp * SPLITCOLS + ct * 32;
        #pragma unroll
        for (int s = 0; s < 4; s++) {
            float x[16];
            #pragma unroll
            for (int rg = 0; rg < 16; rg++) x[rg] = acc[s][rg];
            if (cb == rbase + s * 32) {    // uniform: this tile holds the diagonal of set s
                #pragma unroll
                for (int rg = 0; rg < 16; rg++) {
                    const int c_local = (rg & 3) + 8 * (rg >> 2) + 4 * half;
                    x[rg] = (c_local == lm) ? NEGF : x[rg];
                }
            }
            float t8[8], t4[4], t2[2];
            #pragma unroll
            for (int i = 0; i < 8; i++) t8[i] = fmaxf(x[i], x[i + 8]);
            #pragma unroll
            for (int i = 0; i < 4; i++) t4[i] = fmaxf(t8[i], t8[i + 4]);
            t2[0] = fmaxf(t4[0], t4[2]); t2[1] = fmaxf(t4[1], t4[3]);
            const float tmax = fmaxf(t2[0], t2[1]);
            const float mn = fmaxf(m[s], tmax);
            float acc_l = l[s] * __builtin_exp2f(m[s] - mn);
            float e[16];
            #pragma unroll
            for (int rg = 0; rg < 16; rg++) e[rg] = __builtin_exp2f(x[rg] - mn);
            float s8[8], s4[4], s2[2];
            #pragma unroll
            for (int i = 0; i < 8; i++) s8[i] = e[i] + e[i + 8];
            #pragma unroll
            for (int i = 0; i < 4; i++) s4[i] = s8[i] + s8[i + 4];
            s2[0] = s4[0] + s4[2]; s2[1] = s4[1] + s4[3];
            l[s] = acc_l + (s2[0] + s2[1]);
            m[s] = mn;
        }
    }

    // merge k-halves (lane <-> lane^32: same rows, disjoint col sets)
    float mw[4], lw[4];
    #pragma unroll
    for (int s = 0; s < 4; s++) {
        const float mo = __shfl_xor(m[s], 32);
        const float lo = __shfl_xor(l[s], 32);
        const float mn = fmaxf(m[s], mo);
        lw[s] = l[s] * __builtin_exp2f(m[s] - mn) + lo * __builtin_exp2f(mo - mn);
        mw[s] = mn;
    }
    // lane (lm, half) writes rows for sets s=half and s=2+half -> each row once
    const int rA = rbase + half * 32 + lm;
    Mpart[sp * NROW + rA] = mw[half];
    Lpart[sp * NROW + rA] = lw[half];
    const int rB = rbase + (2 + half) * 32 + lm;
    Mpart[sp * NROW + rB] = mw[2 + half];
    Lpart[sp * NROW + rB] = lw[2 + half];
}

// ---------- kernel 3: merge splits, per-row loss, atomic mean ----------
__global__ __launch_bounds__(256) void k_final(const float* __restrict__ Mpart,
                                               const float* __restrict__ Lpart,
                                               const float* __restrict__ pos,
                                               float* __restrict__ out) {
    __shared__ float red[256];
    const int t = threadIdx.x;
    const int r = blockIdx.x * 256 + t;
    float mm = NEGF, ss = 0.0f;
    #pragma unroll
    for (int sp = 0; sp < NSPLIT; sp++) {
        const float mi = Mpart[sp * NROW + r];
        const float li = Lpart[sp * NROW + r];
        const float mn = fmaxf(mm, mi);
        ss = ss * __builtin_exp2f(mm - mn) + li * __builtin_exp2f(mi - mn);
        mm = mn;
    }
    const float lse = (mm + __builtin_log2f(ss)) * LN2F;
    red[t] = lse - pos[r & (NPAIR - 1)];
    __syncthreads();
    for (int ofs = 128; ofs > 0; ofs >>= 1) {
        if (t < ofs) red[t] += red[t + ofs];
        __syncthreads();
    }
    if (t == 0) atomicAdd(out, red[0] / (float)NROW);
}

extern "C" void kernel_launch(void* const* d_in, const int* in_sizes, int n_in,
                              void* d_out, int out_size, void* d_ws, size_t ws_size,
                              hipStream_t stream) {
    const float* zi = (const float*)d_in[0];
    const float* zj = (const float*)d_in[1];
    __bf16* Zf   = (__bf16*)d_ws;                       // 4 MB fragment-ready
    float* pos   = (float*)((char*)d_ws + (size_t)NROW * DIM * 2);
    float* Mpart = pos + NPAIR;
    float* Lpart = Mpart + NSPLIT * NROW;

    k_convert<<<NPAIR / 4, 256, 0, stream>>>(zi, zj, Zf, pos, (float*)d_out);
    k_lse<<<16 * NSPLIT, 256, 0, stream>>>(Zf, Mpart, Lpart);
    k_final<<<NROW / 256, 256, 0, stream>>>(Mpart, Lpart, pos, (float*)d_out);
}

// Round 4
// 111.270 us; speedup vs baseline: 1.6642x; 1.1130x over previous
//
#include <hip/hip_runtime.h>
#include <hip/hip_bf16.h>

// NT-Xent loss, N=4096, D=256, T=0.5.
// loss = mean_r [ LSE_{c!=r}(2 z_r.z_c) - 2 z_r.z_label(r) ], z = concat(z_i,z_j) (8192x256)
// Flash-style streaming LSE with bf16 MFMA, fragment-ready Z layout.
// R4: amdgpu_waves_per_eu(2,2) pins the register budget at 256 so the 128-VGPR
// resident B-fragment set actually STAYS resident (R2/R3 showed the scheduler
// rematerializing it from L2 every tile -> L2-BW bound). 64 rows/wave, 2 acc
// sets, 4-chunk register double-buffer for the streamed A tiles, no LDS.

typedef __bf16 bf16x8 __attribute__((ext_vector_type(8)));
typedef __bf16 bf16x4 __attribute__((ext_vector_type(4)));
typedef float  f32x16 __attribute__((ext_vector_type(16)));

#define NPAIR 4096
#define NROW  8192
#define DIM   256
#define NSPLIT 16
#define SPLITCOLS 512
#define NTILES (SPLITCOLS / 32)   // 16 tiles of 32 cols per split
#define RBLK  16384               // bytes per 32-row fragment block (32*256*2)
#define NEGF  (-1.0e30f)
// x = dot/T * log2(e) = dot * 2*log2(e); Z pre-scaled by sqrt(2*log2 e)
#define SQSCALE 1.6986437f
#define LN2F    0.6931471805599453f

// ---------- kernel 1: f32 -> bf16 (pre-scaled) into Z_F + positive dots + out zero ----
__global__ __launch_bounds__(256) void k_convert(const float* __restrict__ zi,
                                                 const float* __restrict__ zj,
                                                 __bf16* __restrict__ Zf,
                                                 float* __restrict__ pos,
                                                 float* __restrict__ out) {
    const int w = threadIdx.x >> 6, lane = threadIdx.x & 63;
    const int r = blockIdx.x * 4 + w;
    if (blockIdx.x == 0 && threadIdx.x == 0) out[0] = 0.0f;
    const float4 vi = *(const float4*)(zi + r * DIM + lane * 4);
    const float4 vj = *(const float4*)(zj + r * DIM + lane * 4);
    bf16x4 bi, bj;
    bi[0] = (__bf16)(vi.x * SQSCALE); bi[1] = (__bf16)(vi.y * SQSCALE);
    bi[2] = (__bf16)(vi.z * SQSCALE); bi[3] = (__bf16)(vi.w * SQSCALE);
    bj[0] = (__bf16)(vj.x * SQSCALE); bj[1] = (__bf16)(vj.y * SQSCALE);
    bj[2] = (__bf16)(vj.z * SQSCALE); bj[3] = (__bf16)(vj.w * SQSCALE);
    // lane holds k = lane*4..lane*4+3 -> chunk t = lane>>2, half = (lane>>1)&1, inner = (lane&1)*8 B
    const int t = lane >> 2, h = (lane >> 1) & 1, inner = (lane & 1) * 8;
    char* Zb = (char*)Zf;
    *(bf16x4*)(Zb + (size_t)(r >> 5) * RBLK + t * 1024 + h * 512 + (r & 31) * 16 + inner) = bi;
    const int r2 = r + NPAIR;
    *(bf16x4*)(Zb + (size_t)(r2 >> 5) * RBLK + t * 1024 + h * 512 + (r2 & 31) * 16 + inner) = bj;
    float d = vi.x * vj.x + vi.y * vj.y + vi.z * vj.z + vi.w * vj.w;
    #pragma unroll
    for (int m = 32; m >= 1; m >>= 1) d += __shfl_xor(d, m);
    if (lane == 0) pos[r] = 2.0f * d;   // natural units
}

// ---------- kernel 2: streaming logsumexp ----------
// grid = 32 rowblocks x 16 splits = 512 blocks (2/CU, 2 waves/SIMD). Each wave
// owns 64 rows (2 MFMA B-sets resident in 128 VGPRs) and streams 16 tiles of
// 32 columns through the A-operand straight from L1/L2 (coalesced Z_F loads).
__global__ __launch_bounds__(256) __attribute__((amdgpu_waves_per_eu(2, 2)))
void k_lse(const __bf16* __restrict__ Zf,
           float* __restrict__ Mpart,
           float* __restrict__ Lpart) {
    const int sp = blockIdx.x & (NSPLIT - 1);
    const int rb = blockIdx.x >> 4;          // 0..31
    const int w    = threadIdx.x >> 6;
    const int lane = threadIdx.x & 63;
    const int lm   = lane & 31;
    const int half = lane >> 5;
    const int rbase = rb * 256 + w * 64;
    const char* Zb = (const char*)Zf;
    const int laneoff = half * 512 + lm * 16;

    // resident row fragments: set s covers rows rbase + s*32 + (0..31)
    bf16x8 Bf[2][16];
    #pragma unroll
    for (int s = 0; s < 2; s++)
        #pragma unroll
        for (int t = 0; t < 16; t++)
            Bf[s][t] = *(const bf16x8*)(Zb + (size_t)(rb * 8 + w * 2 + s) * RBLK + t * 1024 + laneoff);

    float m[2] = {NEGF, NEGF}, l[2] = {0.0f, 0.0f};

    const char* Ab = Zb + (size_t)(sp * NTILES) * RBLK + laneoff;

    // 4-chunk register double buffer for the streamed A tile
    bf16x8 P0[4], P1[4];
    #pragma unroll
    for (int t = 0; t < 4; t++) P0[t] = *(const bf16x8*)(Ab + t * 1024);

    for (int ct = 0; ct < NTILES; ct++) {
        const char* At = Ab + (size_t)ct * RBLK;
        f32x16 acc0 = (f32x16)(0.0f);
        f32x16 acc1 = (f32x16)(0.0f);

        #pragma unroll
        for (int t = 0; t < 4; t++) P1[t] = *(const bf16x8*)(At + (4 + t) * 1024);
        #pragma unroll
        for (int t = 0; t < 4; t++) {
            acc0 = __builtin_amdgcn_mfma_f32_32x32x16_bf16(P0[t], Bf[0][t], acc0, 0, 0, 0);
            acc1 = __builtin_amdgcn_mfma_f32_32x32x16_bf16(P0[t], Bf[1][t], acc1, 0, 0, 0);
        }
        #pragma unroll
        for (int t = 0; t < 4; t++) P0[t] = *(const bf16x8*)(At + (8 + t) * 1024);
        #pragma unroll
        for (int t = 0; t < 4; t++) {
            acc0 = __builtin_amdgcn_mfma_f32_32x32x16_bf16(P1[t], Bf[0][4 + t], acc0, 0, 0, 0);
            acc1 = __builtin_amdgcn_mfma_f32_32x32x16_bf16(P1[t], Bf[1][4 + t], acc1, 0, 0, 0);
        }
        #pragma unroll
        for (int t = 0; t < 4; t++) P1[t] = *(const bf16x8*)(At + (12 + t) * 1024);
        #pragma unroll
        for (int t = 0; t < 4; t++) {
            acc0 = __builtin_amdgcn_mfma_f32_32x32x16_bf16(P0[t], Bf[0][8 + t], acc0, 0, 0, 0);
            acc1 = __builtin_amdgcn_mfma_f32_32x32x16_bf16(P0[t], Bf[1][8 + t], acc1, 0, 0, 0);
        }
        // prefetch next tile's first group (last iter reads 16 KB past Z_F: still
        // inside d_ws (pos/Mpart follow), value discarded)
        #pragma unroll
        for (int t = 0; t < 4; t++) P0[t] = *(const bf16x8*)(At + RBLK + t * 1024);
        #pragma unroll
        for (int t = 0; t < 4; t++) {
            acc0 = __builtin_amdgcn_mfma_f32_32x32x16_bf16(P1[t], Bf[0][12 + t], acc0, 0, 0, 0);
            acc1 = __builtin_amdgcn_mfma_f32_32x32x16_bf16(P1[t], Bf[1][12 + t], acc1, 0, 0, 0);
        }

        // epilogue: set s -> row rbase+s*32+lm; lane holds 16 cols (by reg & half)
        const int cb = sp * SPLITCOLS + ct * 32;
        #pragma unroll
        for (int s = 0; s < 2; s++) {
            float x[16];
            #pragma unroll
            for (int rg = 0; rg < 16; rg++) x[rg] = s ? acc1[rg] : acc0[rg];
            if (cb == rbase + s * 32) {   // uniform: this tile holds set-s diagonal
                #pragma unroll
                for (int rg = 0; rg < 16; rg++) {
                    const int c_local = (rg & 3) + 8 * (rg >> 2) + 4 * half;
                    x[rg] = (c_local == lm) ? NEGF : x[rg];
                }
            }
            float t8[8], t4[4], t2[2];
            #pragma unroll
            for (int i = 0; i < 8; i++) t8[i] = fmaxf(x[i], x[i + 8]);
            #pragma unroll
            for (int i = 0; i < 4; i++) t4[i] = fmaxf(t8[i], t8[i + 4]);
            t2[0] = fmaxf(t4[0], t4[2]); t2[1] = fmaxf(t4[1], t4[3]);
            const float tmax = fmaxf(t2[0], t2[1]);
            const float mn = fmaxf(m[s], tmax);
            float acc_l = l[s] * __builtin_exp2f(m[s] - mn);
            float e[16];
            #pragma unroll
            for (int rg = 0; rg < 16; rg++) e[rg] = __builtin_exp2f(x[rg] - mn);
            float s8[8], s4[4], s2[2];
            #pragma unroll
            for (int i = 0; i < 8; i++) s8[i] = e[i] + e[i + 8];
            #pragma unroll
            for (int i = 0; i < 4; i++) s4[i] = s8[i] + s8[i + 4];
            s2[0] = s4[0] + s4[2]; s2[1] = s4[1] + s4[3];
            l[s] = acc_l + (s2[0] + s2[1]);
            m[s] = mn;
        }
    }

    // merge k-halves (lane <-> lane^32: same rows, disjoint col sets)
    float mw[2], lw[2];
    #pragma unroll
    for (int s = 0; s < 2; s++) {
        const float mo = __shfl_xor(m[s], 32);
        const float lo = __shfl_xor(l[s], 32);
        const float mn = fmaxf(m[s], mo);
        lw[s] = l[s] * __builtin_exp2f(m[s] - mn) + lo * __builtin_exp2f(mo - mn);
        mw[s] = mn;
    }
    const int r_out = rbase + half * 32 + lm;   // lane (lm,half) -> set s=half row
    Mpart[sp * NROW + r_out] = mw[half];
    Lpart[sp * NROW + r_out] = lw[half];
}

// ---------- kernel 3: merge splits, per-row loss, atomic mean ----------
__global__ __launch_bounds__(256) void k_final(const float* __restrict__ Mpart,
                                               const float* __restrict__ Lpart,
                                               const float* __restrict__ pos,
                                               float* __restrict__ out) {
    __shared__ float red[256];
    const int t = threadIdx.x;
    const int r = blockIdx.x * 256 + t;
    float mm = NEGF, ss = 0.0f;
    #pragma unroll
    for (int sp = 0; sp < NSPLIT; sp++) {
        const float mi = Mpart[sp * NROW + r];
        const float li = Lpart[sp * NROW + r];
        const float mn = fmaxf(mm, mi);
        ss = ss * __builtin_exp2f(mm - mn) + li * __builtin_exp2f(mi - mn);
        mm = mn;
    }
    const float lse = (mm + __builtin_log2f(ss)) * LN2F;
    red[t] = lse - pos[r & (NPAIR - 1)];
    __syncthreads();
    for (int ofs = 128; ofs > 0; ofs >>= 1) {
        if (t < ofs) red[t] += red[t + ofs];
        __syncthreads();
    }
    if (t == 0) atomicAdd(out, red[0] / (float)NROW);
}

extern "C" void kernel_launch(void* const* d_in, const int* in_sizes, int n_in,
                              void* d_out, int out_size, void* d_ws, size_t ws_size,
                              hipStream_t stream) {
    const float* zi = (const float*)d_in[0];
    const float* zj = (const float*)d_in[1];
    __bf16* Zf   = (__bf16*)d_ws;                       // 4 MB fragment-ready
    float* pos   = (float*)((char*)d_ws + (size_t)NROW * DIM * 2);
    float* Mpart = pos + NPAIR;
    float* Lpart = Mpart + NSPLIT * NROW;

    k_convert<<<NPAIR / 4, 256, 0, stream>>>(zi, zj, Zf, pos, (float*)d_out);
    k_lse<<<32 * NSPLIT, 256, 0, stream>>>(Zf, Mpart, Lpart);
    k_final<<<NROW / 256, 256, 0, stream>>>(Mpart, Lpart, pos, (float*)d_out);
}